// Round 1
// baseline (83.146 us; speedup 1.0000x reference)
//
#include <hip/hip_runtime.h>

// DistillKL 'w' branch forward, B=64, C=1000, T=4.
// loss = -(T^2/B) * sum_{b,i} max(p_t,1e-7) * max(expt*log(min(p_s,1)), log(1e-7))
// where p = exp(x) / (choice * neg_sum + exp(x)), x = y/4,
//   t3[i] = (1/C) sum_k w[k]*relu(x[i]-x[k]),
//   choice = w*exp(-t3) + (1-w), neg_sum = sum_k (1-w[k])*exp(x[k]),
//   expt  = w*min(|(pt1+1)/2 - ps1|,1)^0.25 + (1-w)*min(|pt1/2 - ps1|,1).

#define BN 64
#define CN 1000
#define SPLITS 8
#define CHUNK 125          // ceil(1000/8)
#define THREADS 128
#define NEG_LOG_EPS -16.118095650958319f   // log(1e-7)

__global__ __launch_bounds__(THREADS) void distill_part(
    const float* __restrict__ ys, const float* __restrict__ yt,
    const float* __restrict__ w, float* __restrict__ part)
{
    const int b = blockIdx.x;
    const int s = blockIdx.y;
    const int tid = threadIdx.x;
    const int lane = tid & 63;
    const int wid = tid >> 6;          // 2 waves per block

    __shared__ float xs[CN], xt[CN];       // x = y/4
    __shared__ float xsm[CN], xtm[CN];     // masked: w? x : +1e30 (relu kills it)
    __shared__ float wsh[CN];
    __shared__ float redns[4];             // neg_sum reduction (2 waves x 2 sums)
    __shared__ float redterm[2];           // loss-term reduction

    const float* ysr = ys + b * CN;
    const float* ytr = yt + b * CN;
    const float* wr  = w  + b * CN;

    float ns_s = 0.f, ns_t = 0.f;
    for (int k = tid; k < CN; k += THREADS) {
        float a  = ysr[k] * 0.25f;
        float c2 = ytr[k] * 0.25f;
        float wk = wr[k];
        xs[k] = a; xt[k] = c2; wsh[k] = wk;
        bool pos = (wk != 0.f);
        xsm[k] = pos ? a  : 1e30f;
        xtm[k] = pos ? c2 : 1e30f;
        float nw = 1.f - wk;
        ns_s += nw * expf(a);
        ns_t += nw * expf(c2);
    }
    #pragma unroll
    for (int off = 32; off > 0; off >>= 1) {
        ns_s += __shfl_down(ns_s, off);
        ns_t += __shfl_down(ns_t, off);
    }
    if (lane == 0) { redns[wid * 2] = ns_s; redns[wid * 2 + 1] = ns_t; }
    __syncthreads();
    const float negsum_s = redns[0] + redns[2];
    const float negsum_t = redns[1] + redns[3];

    float term = 0.f;
    const int i = s * CHUNK + tid;
    if (tid < CHUNK && i < CN) {
        const float xsi = xs[i], xti = xt[i];
        float acc_s = 0.f, acc_t = 0.f;
        #pragma unroll 4
        for (int k = 0; k < CN; ++k) {
            acc_s += fmaxf(xsi - xsm[k], 0.f);
            acc_t += fmaxf(xti - xtm[k], 0.f);
        }
        const float t3s = acc_s * (1.0f / CN);
        const float t3t = acc_t * (1.0f / CN);
        const float wi = wsh[i];
        const float ch_s = wi * expf(-t3s) + (1.f - wi);
        const float ch_t = wi * expf(-t3t) + (1.f - wi);
        const float exs = expf(xsi), ext = expf(xti);
        const float p_s = exs / (ch_s * negsum_s + exs);
        const float p_t = ext / (ch_t * negsum_t + ext);
        const float ps1 = fminf(p_s, 1.f);
        const float pt1 = fminf(p_t, 1.f);
        const float vpos = fminf(fabsf((pt1 + 1.f) * 0.5f - ps1), 1.f);
        const float vneg = fminf(fabsf(pt1 * 0.5f - ps1), 1.f);
        const float expt = wi * sqrtf(sqrtf(vpos)) + (1.f - wi) * vneg;
        const float logps = fmaxf(expt * logf(ps1), NEG_LOG_EPS);
        term = fmaxf(p_t, 1e-7f) * logps;
    }
    #pragma unroll
    for (int off = 32; off > 0; off >>= 1) term += __shfl_down(term, off);
    __syncthreads();                    // protect redns reads before reuse-adjacent writes
    if (lane == 0) redterm[wid] = term;
    __syncthreads();
    if (tid == 0) part[b * SPLITS + s] = redterm[0] + redterm[1];
}

__global__ __launch_bounds__(64) void distill_final(
    const float* __restrict__ part, float* __restrict__ out)
{
    const int t = threadIdx.x;
    float v = 0.f;
    for (int j = t; j < BN * SPLITS; j += 64) v += part[j];
    #pragma unroll
    for (int off = 32; off > 0; off >>= 1) v += __shfl_down(v, off);
    if (t == 0) out[0] = -0.25f * v;    // -(T*T)/B = -16/64
}

extern "C" void kernel_launch(void* const* d_in, const int* in_sizes, int n_in,
                              void* d_out, int out_size, void* d_ws, size_t ws_size,
                              hipStream_t stream) {
    const float* ys = (const float*)d_in[0];
    const float* yt = (const float*)d_in[1];
    const float* w  = (const float*)d_in[2];
    float* out  = (float*)d_out;
    float* part = (float*)d_ws;   // BN*SPLITS floats

    dim3 grid(BN, SPLITS);
    distill_part<<<grid, THREADS, 0, stream>>>(ys, yt, w, part);
    distill_final<<<1, 64, 0, stream>>>(part, out);
}